// Round 12
// baseline (180.702 us; speedup 1.0000x reference)
//
#include <hip/hip_runtime.h>

#define N_N 50000
#define N_E 800000
#define NG  128
#define NBKT 782          // ceil(50000/64) buckets of 64 nodes
#define CAP  1536         // slot capacity per bucket (padded mean 1248, sigma ~37)
#define EPB  8192         // edges per k_bin block
#define BINB 98           // ceil(800000/8192)

typedef float4 f4;
typedef __attribute__((ext_vector_type(8))) short bf16x8;
typedef __attribute__((ext_vector_type(4))) float f32x4;

__device__ __forceinline__ unsigned short f2b(float x){
  unsigned int u = __float_as_uint(x);
  u += 0x7fffu + ((u >> 16) & 1u);
  return (unsigned short)(u >> 16);
}
__device__ __forceinline__ float b2f(unsigned short h){
  return __uint_as_float(((unsigned int)h) << 16);
}
__device__ __forceinline__ float2 b2f2(unsigned int u){
  float2 r;
  r.x = __uint_as_float(u << 16);
  r.y = __uint_as_float(u & 0xffff0000u);
  return r;
}

// ---------------- init: Wt transpose-cast + zero counters + zero sentinel rows of xb0/xb1 ----------------
__global__ __launch_bounds__(256) void k_init(const float* __restrict__ W1, const float* __restrict__ W2,
    unsigned short* __restrict__ Wt1, unsigned short* __restrict__ Wt2,
    int* __restrict__ zp, int n4, unsigned int* __restrict__ x0z, unsigned int* __restrict__ x1z){
  int bid = blockIdx.x, t = threadIdx.x;
  int i = bid*256 + t;
  if (bid < 128){
    const float* W = (i < 16384) ? W1 : W2;
    unsigned short* Wt = (i < 16384) ? Wt1 : Wt2;
    int j = i & 16383;
    int k = j >> 7, n = j & 127;
    Wt[n*128 + k] = f2b(W[k*128 + n]);
  } else if (bid == gridDim.x - 1){
    if (t < 64)       x0z[(size_t)N_N*64 + t] = 0;        // sentinel row of xb0
    else if (t < 128) x1z[(size_t)N_N*64 + (t-64)] = 0;   // sentinel row of xb1
  } else {
    int z = i - 128*256;
    if (z < n4) zp[z] = 0;
  }
}

// ---------------- block-local counting sort into coarse buckets ----------------
__global__ __launch_bounds__(512) void k_bin(const int* __restrict__ ei,
    int* __restrict__ bcnt, unsigned int* __restrict__ bins){
  __shared__ unsigned int sorted[EPB];   // 32 KB
  __shared__ int hist[NBKT];
  __shared__ int lstart[NBKT];
  __shared__ int lcur[NBKT];
  __shared__ int gbase[NBKT];
  __shared__ int segsum[16];
  int t = threadIdx.x;
  int e0 = blockIdx.x * EPB;
  int n = N_E - e0; if (n > EPB) n = EPB;
  for (int i=t; i<NBKT; i+=512) hist[i] = 0;
  __syncthreads();
  for (int i=t; i<n; i+=512){
    int d = ei[N_E + e0 + i];
    atomicAdd(&hist[d>>6], 1);
  }
  __syncthreads();
  int w = t >> 6, lane = t & 63;
  for (int seg = w; seg < 13; seg += 8){
    int idx = seg*64 + lane;
    int v = (idx < NBKT) ? hist[idx] : 0;
    int x = v;
    #pragma unroll
    for (int dd=1; dd<64; dd<<=1){ int y = __shfl_up(x, dd, 64); if (lane >= dd) x += y; }
    if (idx < NBKT) lstart[idx] = x - v;
    if (lane == 63) segsum[seg] = x;
  }
  __syncthreads();
  if (t == 0){ int s=0; for (int j=0;j<13;j++){ int v=segsum[j]; segsum[j]=s; s+=v; } }
  __syncthreads();
  for (int i=t; i<NBKT; i+=512){ int v = lstart[i] + segsum[i>>6]; lstart[i] = v; lcur[i] = v; }
  __syncthreads();
  for (int i=t; i<n; i+=512){
    int s = ei[e0 + i], d = ei[N_E + e0 + i];
    int pos = atomicAdd(&lcur[d>>6], 1);
    sorted[pos] = ((unsigned int)s << 16) | (unsigned int)d;
  }
  __syncthreads();
  for (int i=t; i<NBKT; i+=512) gbase[i] = atomicAdd(&bcnt[i], hist[i]);
  __syncthreads();
  for (int i=t; i<n; i+=512){
    unsigned int item = sorted[i];
    int d = item & 0xffff;
    int b = d >> 6;
    bins[b*CAP + gbase[b] + (i - lstart[b])] = item;
  }
}

// ---------------- fused: per-bucket CSR finalize (8-padded) + preprocess MLP, out = x1*dinv (bf16) ----------------
__global__ __launch_bounds__(256) void k_csrpre(const unsigned int* __restrict__ bins,
    const int* __restrict__ bcnt, int2* __restrict__ sd, float* __restrict__ dinv,
    int* __restrict__ ssrc,
    const float* __restrict__ emb, const float* __restrict__ pose,
    const float* __restrict__ W, const float* __restrict__ bias, unsigned short* __restrict__ out){
  __shared__ float As[64*64];
  __shared__ float Bs[64*128];
  __shared__ int hist[64];
  __shared__ int lcur[64];
  __shared__ float sdv[64];
  __shared__ int cnt_s;
  int b = blockIdx.x, t = threadIdx.x;

  // ---- CSR phase ----
  if (t < 64) hist[t] = 0;
  if (t == 0) cnt_s = bcnt[b];
  __syncthreads();
  int cnt = cnt_s;
  const unsigned int* P = bins + b*CAP;
  for (int j=t; j<cnt; j+=256) atomicAdd(&hist[P[j] & 63], 1);
  __syncthreads();
  if (t < 64){
    int v = hist[t];
    int ph = (v + 7) & ~7;               // padded to multiple of 8
    int x = ph;
    #pragma unroll
    for (int dd=1; dd<64; dd<<=1){ int y = __shfl_up(x, dd, 64); if (t >= dd) x += y; }
    int excl = x - ph;
    int node = (b<<6) + t;
    float dv = rsqrtf((float)(v + 1));
    if (node < N_N){
      sd[node] = make_int2(b*CAP + excl, ph);          // padded count
      dinv[node] = dv;
    }
    sdv[t] = dv;
    lcur[t] = b*CAP + excl;
    for (int j=v; j<ph; j++) ssrc[b*CAP + excl + j] = N_N;   // sentinel pad
  }
  __syncthreads();
  for (int j=t; j<cnt; j+=256){
    unsigned int p = P[j];
    int pos = atomicAdd(&lcur[p & 63], 1);
    ssrc[pos] = (int)(p >> 16);
  }

  // ---- preprocess MLP phase ----
  int row0 = b*64;
  for (int j=t; j<2048; j+=256) ((f4*)Bs)[j] = ((const f4*)W)[j];
  for (int j=t; j<1024; j+=256){
    int r = j>>4, c4 = j&15;
    int gr = row0 + r;
    f4 a = {0.f,0.f,0.f,0.f};
    if (gr < N_N){
      f4 e0 = ((const f4*)emb)[gr*16 + c4];
      f4 p0 = ((const f4*)pose)[gr*16 + c4];
      a.x = e0.x+p0.x; a.y = e0.y+p0.y; a.z = e0.z+p0.z; a.w = e0.w+p0.w;
    }
    ((f4*)As)[j] = a;
  }
  __syncthreads();
  int cg = t&31, rg = t>>5;
  float acc[8][4] = {};
  for (int k=0;k<64;k++){
    f4 bb = ((f4*)Bs)[k*32 + cg];
    #pragma unroll
    for (int i=0;i<8;i++){
      float a = As[(rg*8+i)*64 + k];
      acc[i][0] = fmaf(a,bb.x,acc[i][0]); acc[i][1] = fmaf(a,bb.y,acc[i][1]);
      acc[i][2] = fmaf(a,bb.z,acc[i][2]); acc[i][3] = fmaf(a,bb.w,acc[i][3]);
    }
  }
  f4 bb = ((const f4*)bias)[cg];
  for (int i=0;i<8;i++){
    int gr = row0 + rg*8 + i;
    if (gr < N_N){
      float dv = sdv[rg*8 + i];
      ushort4 o;
      o.x = f2b(fmaxf(acc[i][0]+bb.x, 0.f) * dv);
      o.y = f2b(fmaxf(acc[i][1]+bb.y, 0.f) * dv);
      o.z = f2b(fmaxf(acc[i][2]+bb.z, 0.f) * dv);
      o.w = f2b(fmaxf(acc[i][3]+bb.w, 0.f) * dv);
      *(ushort4*)&out[gr*128 + cg*4] = o;
    }
  }
}

// ---------------- fused GCN layer: gather+sum x~ -> tile MFMA @ W -> bias/relu(/dinv) -> bf16 out ----------------
// block = 16 nodes (4 waves, 4 nodes each, 1 wave per node at a time). Padded CSR, sentinel row N_N = 0.
__global__ __launch_bounds__(256) void k_layer(const unsigned int* __restrict__ tin,  // [N_N+1][64] dwords
    const int2* __restrict__ sd, const int* __restrict__ ssrc, const float* __restrict__ dinv,
    const unsigned short* __restrict__ Wt, const float* __restrict__ bias,
    unsigned short* __restrict__ outp, int scale_out){
  __shared__ unsigned int ts[16*64];   // 16 x 128 bf16, 16B-chunk XOR swizzled
  __shared__ float sdv[16];
  int t = threadIdx.x;
  int wid = t >> 6, l = t & 63;
  int tile0 = blockIdx.x * 16;
  #pragma unroll
  for (int i=0; i<4; i++){
    int r = wid*4 + i;
    int v = tile0 + r;
    float2 acc = b2f2(tin[(v<<6) + l]);          // self term x~_v
    int2 s_d = sd[v];
    int s = s_d.x, pc = s_d.y;
    for (int k=0; k<pc; k+=8){
      int4 ua = *(const int4*)(ssrc + s + k);
      int4 ub = *(const int4*)(ssrc + s + k + 4);
      unsigned int m0 = tin[(ua.x<<6)+l], m1 = tin[(ua.y<<6)+l];
      unsigned int m2 = tin[(ua.z<<6)+l], m3 = tin[(ua.w<<6)+l];
      unsigned int m4 = tin[(ub.x<<6)+l], m5 = tin[(ub.y<<6)+l];
      unsigned int m6 = tin[(ub.z<<6)+l], m7 = tin[(ub.w<<6)+l];
      float2 f0=b2f2(m0), f1=b2f2(m1), f2=b2f2(m2), f3=b2f2(m3);
      float2 f4_=b2f2(m4), f5=b2f2(m5), f6=b2f2(m6), f7=b2f2(m7);
      acc.x += ((f0.x+f1.x)+(f2.x+f3.x)) + ((f4_.x+f5.x)+(f6.x+f7.x));
      acc.y += ((f0.y+f1.y)+(f2.y+f3.y)) + ((f4_.y+f5.y)+(f6.y+f7.y));
    }
    float dv = dinv[v];
    if (l == 0) sdv[r] = dv;
    unsigned int pk = (unsigned int)f2b(dv*acc.x) | ((unsigned int)f2b(dv*acc.y) << 16);
    ts[r*64 + (((l>>2) ^ (r&7))<<2) + (l&3)] = pk;   // swizzled stage
  }
  __syncthreads();
  // MFMA: wave wid owns output cols wid*32 .. wid*32+31 (2 n-frags), all 16 rows
  int lr = l & 15, kg = l >> 4;
  f32x4 acc0 = {0.f,0.f,0.f,0.f}, acc1 = {0.f,0.f,0.f,0.f};
  int n0 = wid*32 + lr, n1 = n0 + 16;
  #pragma unroll
  for (int ks=0; ks<4; ks++){
    bf16x8 a = *(bf16x8*)&ts[lr*64 + ((((ks<<2)+kg) ^ (lr&7))<<2)];
    bf16x8 b0 = *(const bf16x8*)&Wt[n0*128 + ks*32 + kg*8];
    bf16x8 b1 = *(const bf16x8*)&Wt[n1*128 + ks*32 + kg*8];
    acc0 = __builtin_amdgcn_mfma_f32_16x16x32_bf16(a, b0, acc0, 0, 0, 0);
    acc1 = __builtin_amdgcn_mfma_f32_16x16x32_bf16(a, b1, acc1, 0, 0, 0);
  }
  float b0v = bias[n0], b1v = bias[n1];
  #pragma unroll
  for (int r4=0; r4<4; r4++){
    int row = kg*4 + r4;                 // C layout: row = (lane>>4)*4 + reg
    int v = tile0 + row;
    float dv = scale_out ? sdv[row] : 1.f;
    outp[v*128 + n0] = f2b(fmaxf(acc0[r4]+b0v, 0.f) * dv);
    outp[v*128 + n1] = f2b(fmaxf(acc1[r4]+b1v, 0.f) * dv);
  }
}

// ---------------- mean pool over sorted batch (bf16 row-major in) ----------------
__global__ __launch_bounds__(128) void k_pool(const unsigned short* __restrict__ x, const int* __restrict__ batch,
    float* __restrict__ gsum, float* __restrict__ gcnt){
  int c = threadIdx.x;
  int n0 = blockIdx.x*128;
  int n1 = n0 + 128; if (n1 > N_N) n1 = N_N;
  int cur = batch[n0];
  float acc = 0.f, cnt = 0.f;
  for (int i=n0; i<n1; i++){
    int b = batch[i];
    if (b != cur){
      atomicAdd(&gsum[cur*128+c], acc);
      if (c == 0) atomicAdd(&gcnt[cur], cnt);
      acc = 0.f; cnt = 0.f; cur = b;
    }
    acc += b2f(x[i*128+c]);
    cnt += 1.f;
  }
  atomicAdd(&gsum[cur*128+c], acc);
  if (c == 0) atomicAdd(&gcnt[cur], cnt);
}

// ---------------- head MLP (128->64->32, relu both) ----------------
__global__ __launch_bounds__(64) void k_head(const float* __restrict__ gsum, const float* __restrict__ gcnt,
    const float* __restrict__ W1, const float* __restrict__ b1,
    const float* __restrict__ W2, const float* __restrict__ b2, float* __restrict__ out){
  __shared__ float pooled[128];
  __shared__ float h1[64];
  int g = blockIdx.x, t = threadIdx.x;
  float cnt = fmaxf(gcnt[g], 1.f);
  pooled[t]      = gsum[g*128 + t] / cnt;
  pooled[t + 64] = gsum[g*128 + 64 + t] / cnt;
  __syncthreads();
  float a = b1[t];
  for (int k=0; k<128; k++) a = fmaf(pooled[k], W1[k*64 + t], a);
  h1[t] = fmaxf(a, 0.f);
  __syncthreads();
  if (t < 32){
    float o = b2[t];
    for (int k=0; k<64; k++) o = fmaf(h1[k], W2[k*32 + t], o);
    out[g*32 + t] = fmaxf(o, 0.f);
  }
}

extern "C" void kernel_launch(void* const* d_in, const int* in_sizes, int n_in,
                              void* d_out, int out_size, void* d_ws, size_t ws_size,
                              hipStream_t stream){
  const float* emb  = (const float*)d_in[0];
  const float* pose = (const float*)d_in[1];
  const int*   ei   = (const int*)d_in[2];
  const int*   batch= (const int*)d_in[3];
  const float* Wpre = (const float*)d_in[4];
  const float* bpre = (const float*)d_in[5];
  const float* Wg1  = (const float*)d_in[6];
  const float* bg1  = (const float*)d_in[7];
  const float* Wg2  = (const float*)d_in[8];
  const float* bg2  = (const float*)d_in[9];
  const float* Wh1  = (const float*)d_in[10];
  const float* bh1  = (const float*)d_in[11];
  const float* Wh2  = (const float*)d_in[12];
  const float* bh2  = (const float*)d_in[13];
  float* out = (float*)d_out;

  char* ws = (char*)d_ws;
  unsigned short* xb0 = (unsigned short*)(ws + 0);          // 12,800,256 ((N_N+1) rows)
  unsigned short* xb1 = (unsigned short*)(ws + 12800256);   // 12,800,256
  unsigned short* Wt1 = (unsigned short*)(ws + 25600512);   // 32,768
  unsigned short* Wt2 = (unsigned short*)(ws + 25633280);   // 32,768
  int2*  sd   = (int2*) (ws + 25666048);   // 400,000
  float* dinv = (float*)(ws + 26066048);   // 200,000
  int*   ssrc = (int*)  (ws + 26266048);   // NBKT*CAP*4 = 4,804,608
  unsigned int* bins = (unsigned int*)(ws + 31070656);   // 4,804,608
  // contiguous zero region: bcnt | gsum | gcnt
  int*   bcnt = (int*)  (ws + 35875264);   // 3,136
  float* gsum = (float*)(ws + 35878400);   // 65,536
  float* gcnt = (float*)(ws + 35943936);   // 512

  const int ZN = (3136 + 65536 + 512) / 4;   // 17,296 ints
  const int ZB = (ZN + 255)/256;             // 68 blocks

  k_init<<<128 + ZB + 1, 256, 0, stream>>>(Wg1, Wg2, Wt1, Wt2, bcnt, ZN,
                                           (unsigned int*)xb0, (unsigned int*)xb1);

  k_bin<<<BINB, 512, 0, stream>>>(ei, bcnt, bins);
  k_csrpre<<<NBKT, 256, 0, stream>>>(bins, bcnt, sd, dinv, ssrc,
                                     emb, pose, Wpre, bpre, xb0);                 // CSR + x1~ -> xb0

  k_layer<<<N_N/16, 256, 0, stream>>>((const unsigned int*)xb0, sd, ssrc, dinv,
                                      Wt1, bg1, xb1, 1);                          // x2~ -> xb1
  k_layer<<<N_N/16, 256, 0, stream>>>((const unsigned int*)xb1, sd, ssrc, dinv,
                                      Wt2, bg2, xb0, 0);                          // x3 -> xb0

  k_pool<<<(N_N+127)/128, 128, 0, stream>>>(xb0, batch, gsum, gcnt);
  k_head<<<NG, 64, 0, stream>>>(gsum, gcnt, Wh1, bh1, Wh2, bh2, out);
}

// Round 14
// 177.379 us; speedup vs baseline: 1.0187x; 1.0187x over previous
//
#include <hip/hip_runtime.h>

#define N_N 50000
#define N_E 800000
#define NG  128
#define NBKT 782          // ceil(50000/64) buckets of 64 nodes
#define CAP  1536         // slot capacity per bucket (padded mean 1248, sigma ~37)
#define EPB  8192         // edges per k_bin block
#define BINB 98           // ceil(800000/8192)

typedef float4 f4;
typedef __attribute__((ext_vector_type(8))) short bf16x8;
typedef __attribute__((ext_vector_type(4))) float f32x4;

__device__ __forceinline__ unsigned short f2b(float x){
  unsigned int u = __float_as_uint(x);
  u += 0x7fffu + ((u >> 16) & 1u);
  return (unsigned short)(u >> 16);
}
__device__ __forceinline__ float b2f(unsigned short h){
  return __uint_as_float(((unsigned int)h) << 16);
}
__device__ __forceinline__ float2 b2f2(unsigned int u){
  float2 r;
  r.x = __uint_as_float(u << 16);
  r.y = __uint_as_float(u & 0xffff0000u);
  return r;
}

// ---------------- init: Wt transpose-cast + zero counters + zero sentinel rows of xb0/xb1 ----------------
__global__ __launch_bounds__(256) void k_init(const float* __restrict__ W1, const float* __restrict__ W2,
    unsigned short* __restrict__ Wt1, unsigned short* __restrict__ Wt2,
    int* __restrict__ zp, int n4, unsigned int* __restrict__ x0z, unsigned int* __restrict__ x1z){
  int bid = blockIdx.x, t = threadIdx.x;
  int i = bid*256 + t;
  if (bid < 128){
    const float* W = (i < 16384) ? W1 : W2;
    unsigned short* Wt = (i < 16384) ? Wt1 : Wt2;
    int j = i & 16383;
    int k = j >> 7, n = j & 127;
    Wt[n*128 + k] = f2b(W[k*128 + n]);
  } else if (bid == gridDim.x - 1){
    if (t < 64)       x0z[(size_t)N_N*64 + t] = 0;        // sentinel row of xb0
    else if (t < 128) x1z[(size_t)N_N*64 + (t-64)] = 0;   // sentinel row of xb1
  } else {
    int z = i - 128*256;
    if (z < n4) zp[z] = 0;
  }
}

// ---------------- block-local counting sort into coarse buckets ----------------
__global__ __launch_bounds__(512) void k_bin(const int* __restrict__ ei,
    int* __restrict__ bcnt, unsigned int* __restrict__ bins){
  __shared__ unsigned int sorted[EPB];   // 32 KB
  __shared__ int hist[NBKT];
  __shared__ int lstart[NBKT];
  __shared__ int lcur[NBKT];
  __shared__ int gbase[NBKT];
  __shared__ int segsum[16];
  int t = threadIdx.x;
  int e0 = blockIdx.x * EPB;
  int n = N_E - e0; if (n > EPB) n = EPB;
  for (int i=t; i<NBKT; i+=512) hist[i] = 0;
  __syncthreads();
  for (int i=t; i<n; i+=512){
    int d = ei[N_E + e0 + i];
    atomicAdd(&hist[d>>6], 1);
  }
  __syncthreads();
  int w = t >> 6, lane = t & 63;
  for (int seg = w; seg < 13; seg += 8){
    int idx = seg*64 + lane;
    int v = (idx < NBKT) ? hist[idx] : 0;
    int x = v;
    #pragma unroll
    for (int dd=1; dd<64; dd<<=1){ int y = __shfl_up(x, dd, 64); if (lane >= dd) x += y; }
    if (idx < NBKT) lstart[idx] = x - v;
    if (lane == 63) segsum[seg] = x;
  }
  __syncthreads();
  if (t == 0){ int s=0; for (int j=0;j<13;j++){ int v=segsum[j]; segsum[j]=s; s+=v; } }
  __syncthreads();
  for (int i=t; i<NBKT; i+=512){ int v = lstart[i] + segsum[i>>6]; lstart[i] = v; lcur[i] = v; }
  __syncthreads();
  for (int i=t; i<n; i+=512){
    int s = ei[e0 + i], d = ei[N_E + e0 + i];
    int pos = atomicAdd(&lcur[d>>6], 1);
    sorted[pos] = ((unsigned int)s << 16) | (unsigned int)d;
  }
  __syncthreads();
  for (int i=t; i<NBKT; i+=512) gbase[i] = atomicAdd(&bcnt[i], hist[i]);
  __syncthreads();
  for (int i=t; i<n; i+=512){
    unsigned int item = sorted[i];
    int d = item & 0xffff;
    int b = d >> 6;
    bins[b*CAP + gbase[b] + (i - lstart[b])] = item;
  }
}

// ---------------- fused: per-bucket CSR finalize (8-padded) + preprocess MLP, out = x1*dinv (bf16) ----------------
__global__ __launch_bounds__(256) void k_csrpre(const unsigned int* __restrict__ bins,
    const int* __restrict__ bcnt, int2* __restrict__ sd, float* __restrict__ dinv,
    int* __restrict__ ssrc,
    const float* __restrict__ emb, const float* __restrict__ pose,
    const float* __restrict__ W, const float* __restrict__ bias, unsigned short* __restrict__ out){
  __shared__ float As[64*64];
  __shared__ float Bs[64*128];
  __shared__ int hist[64];
  __shared__ int lcur[64];
  __shared__ float sdv[64];
  __shared__ int cnt_s;
  int b = blockIdx.x, t = threadIdx.x;

  // ---- CSR phase ----
  if (t < 64) hist[t] = 0;
  if (t == 0) cnt_s = bcnt[b];
  __syncthreads();
  int cnt = cnt_s;
  const unsigned int* P = bins + b*CAP;
  for (int j=t; j<cnt; j+=256) atomicAdd(&hist[P[j] & 63], 1);
  __syncthreads();
  if (t < 64){
    int v = hist[t];
    int ph = (v + 7) & ~7;               // padded to multiple of 8
    int x = ph;
    #pragma unroll
    for (int dd=1; dd<64; dd<<=1){ int y = __shfl_up(x, dd, 64); if (t >= dd) x += y; }
    int excl = x - ph;
    int node = (b<<6) + t;
    float dv = rsqrtf((float)(v + 1));
    if (node < N_N){
      sd[node] = make_int2(b*CAP + excl, ph);          // padded count
      dinv[node] = dv;
    }
    sdv[t] = dv;
    lcur[t] = b*CAP + excl;
    for (int j=v; j<ph; j++) ssrc[b*CAP + excl + j] = N_N;   // sentinel pad
  }
  __syncthreads();
  for (int j=t; j<cnt; j+=256){
    unsigned int p = P[j];
    int pos = atomicAdd(&lcur[p & 63], 1);
    ssrc[pos] = (int)(p >> 16);
  }

  // ---- preprocess MLP phase ----
  int row0 = b*64;
  for (int j=t; j<2048; j+=256) ((f4*)Bs)[j] = ((const f4*)W)[j];
  for (int j=t; j<1024; j+=256){
    int r = j>>4, c4 = j&15;
    int gr = row0 + r;
    f4 a = {0.f,0.f,0.f,0.f};
    if (gr < N_N){
      f4 e0 = ((const f4*)emb)[gr*16 + c4];
      f4 p0 = ((const f4*)pose)[gr*16 + c4];
      a.x = e0.x+p0.x; a.y = e0.y+p0.y; a.z = e0.z+p0.z; a.w = e0.w+p0.w;
    }
    ((f4*)As)[j] = a;
  }
  __syncthreads();
  int cg = t&31, rg = t>>5;
  float acc[8][4] = {};
  for (int k=0;k<64;k++){
    f4 bb = ((f4*)Bs)[k*32 + cg];
    #pragma unroll
    for (int i=0;i<8;i++){
      float a = As[(rg*8+i)*64 + k];
      acc[i][0] = fmaf(a,bb.x,acc[i][0]); acc[i][1] = fmaf(a,bb.y,acc[i][1]);
      acc[i][2] = fmaf(a,bb.z,acc[i][2]); acc[i][3] = fmaf(a,bb.w,acc[i][3]);
    }
  }
  f4 bb = ((const f4*)bias)[cg];
  for (int i=0;i<8;i++){
    int gr = row0 + rg*8 + i;
    if (gr < N_N){
      float dv = sdv[rg*8 + i];
      ushort4 o;
      o.x = f2b(fmaxf(acc[i][0]+bb.x, 0.f) * dv);
      o.y = f2b(fmaxf(acc[i][1]+bb.y, 0.f) * dv);
      o.z = f2b(fmaxf(acc[i][2]+bb.z, 0.f) * dv);
      o.w = f2b(fmaxf(acc[i][3]+bb.w, 0.f) * dv);
      *(ushort4*)&out[gr*128 + cg*4] = o;
    }
  }
}

#define GATHER8(dst, ia, ib) \
  dst##0 = tin[(ia.x<<6)+l]; dst##1 = tin[(ia.y<<6)+l]; \
  dst##2 = tin[(ia.z<<6)+l]; dst##3 = tin[(ia.w<<6)+l]; \
  dst##4 = tin[(ib.x<<6)+l]; dst##5 = tin[(ib.y<<6)+l]; \
  dst##6 = tin[(ib.z<<6)+l]; dst##7 = tin[(ib.w<<6)+l];

#define CONSUME8(acc, src) { \
  float2 q0_=b2f2(src##0), q1_=b2f2(src##1), q2_=b2f2(src##2), q3_=b2f2(src##3); \
  float2 q4_=b2f2(src##4), q5_=b2f2(src##5), q6_=b2f2(src##6), q7_=b2f2(src##7); \
  acc.x += ((q0_.x+q1_.x)+(q2_.x+q3_.x)) + ((q4_.x+q5_.x)+(q6_.x+q7_.x)); \
  acc.y += ((q0_.y+q1_.y)+(q2_.y+q3_.y)) + ((q4_.y+q5_.y)+(q6_.y+q7_.y)); }

// ---------------- fused GCN layer: interleaved pipelined gather -> tile MFMA @ W -> epilogue ----------------
// block = 16 nodes (4 waves x 4 nodes). Phase A launches 8 gathers for ALL 4 nodes (+4 self rows)
// -> ~36 loads in flight; phase B drains each node with a 1-deep software pipeline.
__global__ __launch_bounds__(256) void k_layer(const unsigned int* __restrict__ tin,  // [N_N+1][64] dwords
    const int2* __restrict__ sd, const int* __restrict__ ssrc, const float* __restrict__ dinv,
    const unsigned short* __restrict__ Wt, const float* __restrict__ bias,
    unsigned short* __restrict__ outp, int scale_out){
  __shared__ unsigned int ts[16*64];   // 16 x 128 bf16, 16B-chunk XOR swizzled
  __shared__ float sdvs[16];
  int t = threadIdx.x;
  int wid = t >> 6, l = t & 63;
  int tile0 = blockIdx.x * 16;
  int v0 = tile0 + wid*4;

  int ss0, ss1, ss2, ss3, pc0, pc1, pc2, pc3;
  { int2 e0 = sd[v0];   ss0 = e0.x; pc0 = e0.y;
    int2 e1 = sd[v0+1]; ss1 = e1.x; pc1 = e1.y;
    int2 e2 = sd[v0+2]; ss2 = e2.x; pc2 = e2.y;
    int2 e3 = sd[v0+3]; ss3 = e3.x; pc3 = e3.y; }

  // self rows (launch early)
  unsigned int sf0 = tin[((v0  )<<6)+l];
  unsigned int sf1 = tin[((v0+1)<<6)+l];
  unsigned int sf2 = tin[((v0+2)<<6)+l];
  unsigned int sf3 = tin[((v0+3)<<6)+l];

  // ---- phase A: first 8 gathers per node, all issued back-to-back ----
  unsigned int a0,a1,a2,a3,a4,a5,a6,a7;
  unsigned int b0,b1,b2,b3,b4,b5,b6,b7;
  unsigned int c0,c1,c2,c3,c4,c5,c6,c7;
  unsigned int d0,d1,d2,d3,d4,d5,d6,d7;
  if (pc0 > 0){ int4 ia = *(const int4*)(ssrc+ss0); int4 ib = *(const int4*)(ssrc+ss0+4); GATHER8(a, ia, ib) }
  if (pc1 > 0){ int4 ia = *(const int4*)(ssrc+ss1); int4 ib = *(const int4*)(ssrc+ss1+4); GATHER8(b, ia, ib) }
  if (pc2 > 0){ int4 ia = *(const int4*)(ssrc+ss2); int4 ib = *(const int4*)(ssrc+ss2+4); GATHER8(c, ia, ib) }
  if (pc3 > 0){ int4 ia = *(const int4*)(ssrc+ss3); int4 ib = *(const int4*)(ssrc+ss3+4); GATHER8(d, ia, ib) }

  // ---- phase B: drain each node with 1-deep pipeline ----
  float2 acc0 = b2f2(sf0), acc1 = b2f2(sf1), acc2 = b2f2(sf2), acc3 = b2f2(sf3);
  unsigned int n0,n1,n2,n3,n4,n5,n6,n7;
  if (pc0 > 0){
    for (int k=8; k<pc0; k+=8){
      int4 ia = *(const int4*)(ssrc+ss0+k); int4 ib = *(const int4*)(ssrc+ss0+k+4);
      GATHER8(n, ia, ib)
      CONSUME8(acc0, a)
      a0=n0;a1=n1;a2=n2;a3=n3;a4=n4;a5=n5;a6=n6;a7=n7;
    }
    CONSUME8(acc0, a)
  }
  if (pc1 > 0){
    for (int k=8; k<pc1; k+=8){
      int4 ia = *(const int4*)(ssrc+ss1+k); int4 ib = *(const int4*)(ssrc+ss1+k+4);
      GATHER8(n, ia, ib)
      CONSUME8(acc1, b)
      b0=n0;b1=n1;b2=n2;b3=n3;b4=n4;b5=n5;b6=n6;b7=n7;
    }
    CONSUME8(acc1, b)
  }
  if (pc2 > 0){
    for (int k=8; k<pc2; k+=8){
      int4 ia = *(const int4*)(ssrc+ss2+k); int4 ib = *(const int4*)(ssrc+ss2+k+4);
      GATHER8(n, ia, ib)
      CONSUME8(acc2, c)
      c0=n0;c1=n1;c2=n2;c3=n3;c4=n4;c5=n5;c6=n6;c7=n7;
    }
    CONSUME8(acc2, c)
  }
  if (pc3 > 0){
    for (int k=8; k<pc3; k+=8){
      int4 ia = *(const int4*)(ssrc+ss3+k); int4 ib = *(const int4*)(ssrc+ss3+k+4);
      GATHER8(n, ia, ib)
      CONSUME8(acc3, d)
      d0=n0;d1=n1;d2=n2;d3=n3;d4=n4;d5=n5;d6=n6;d7=n7;
    }
    CONSUME8(acc3, d)
  }

  // ---- stage into LDS (swizzled), then MFMA ----
  float dv0 = dinv[v0], dv1 = dinv[v0+1], dv2 = dinv[v0+2], dv3 = dinv[v0+3];
  if (l == 0){ sdvs[wid*4]=dv0; sdvs[wid*4+1]=dv1; sdvs[wid*4+2]=dv2; sdvs[wid*4+3]=dv3; }
  {
    int r = wid*4;
    ts[(r  )*64 + (((l>>2) ^ ((r  )&7))<<2) + (l&3)] = (unsigned int)f2b(dv0*acc0.x) | ((unsigned int)f2b(dv0*acc0.y) << 16);
    ts[(r+1)*64 + (((l>>2) ^ ((r+1)&7))<<2) + (l&3)] = (unsigned int)f2b(dv1*acc1.x) | ((unsigned int)f2b(dv1*acc1.y) << 16);
    ts[(r+2)*64 + (((l>>2) ^ ((r+2)&7))<<2) + (l&3)] = (unsigned int)f2b(dv2*acc2.x) | ((unsigned int)f2b(dv2*acc2.y) << 16);
    ts[(r+3)*64 + (((l>>2) ^ ((r+3)&7))<<2) + (l&3)] = (unsigned int)f2b(dv3*acc3.x) | ((unsigned int)f2b(dv3*acc3.y) << 16);
  }
  __syncthreads();
  int lr = l & 15, kg = l >> 4;
  f32x4 m0 = {0.f,0.f,0.f,0.f}, m1 = {0.f,0.f,0.f,0.f};
  int col0 = wid*32 + lr, col1 = col0 + 16;
  #pragma unroll
  for (int ks=0; ks<4; ks++){
    bf16x8 a = *(bf16x8*)&ts[lr*64 + ((((ks<<2)+kg) ^ (lr&7))<<2)];
    bf16x8 w0 = *(const bf16x8*)&Wt[col0*128 + ks*32 + kg*8];
    bf16x8 w1 = *(const bf16x8*)&Wt[col1*128 + ks*32 + kg*8];
    m0 = __builtin_amdgcn_mfma_f32_16x16x32_bf16(a, w0, m0, 0, 0, 0);
    m1 = __builtin_amdgcn_mfma_f32_16x16x32_bf16(a, w1, m1, 0, 0, 0);
  }
  float bv0 = bias[col0], bv1 = bias[col1];
  #pragma unroll
  for (int r4=0; r4<4; r4++){
    int row = kg*4 + r4;                 // C layout: row = (lane>>4)*4 + reg
    int v = tile0 + row;
    float dv = scale_out ? sdvs[row] : 1.f;
    outp[v*128 + col0] = f2b(fmaxf(m0[r4]+bv0, 0.f) * dv);
    outp[v*128 + col1] = f2b(fmaxf(m1[r4]+bv1, 0.f) * dv);
  }
}

// ---------------- mean pool over sorted batch (bf16 row-major in) ----------------
__global__ __launch_bounds__(128) void k_pool(const unsigned short* __restrict__ x, const int* __restrict__ batch,
    float* __restrict__ gsum, float* __restrict__ gcnt){
  int c = threadIdx.x;
  int n0 = blockIdx.x*128;
  int n1 = n0 + 128; if (n1 > N_N) n1 = N_N;
  int cur = batch[n0];
  float acc = 0.f, cnt = 0.f;
  for (int i=n0; i<n1; i++){
    int b = batch[i];
    if (b != cur){
      atomicAdd(&gsum[cur*128+c], acc);
      if (c == 0) atomicAdd(&gcnt[cur], cnt);
      acc = 0.f; cnt = 0.f; cur = b;
    }
    acc += b2f(x[i*128+c]);
    cnt += 1.f;
  }
  atomicAdd(&gsum[cur*128+c], acc);
  if (c == 0) atomicAdd(&gcnt[cur], cnt);
}

// ---------------- head MLP (128->64->32, relu both) ----------------
__global__ __launch_bounds__(64) void k_head(const float* __restrict__ gsum, const float* __restrict__ gcnt,
    const float* __restrict__ W1, const float* __restrict__ b1,
    const float* __restrict__ W2, const float* __restrict__ b2, float* __restrict__ out){
  __shared__ float pooled[128];
  __shared__ float h1[64];
  int g = blockIdx.x, t = threadIdx.x;
  float cnt = fmaxf(gcnt[g], 1.f);
  pooled[t]      = gsum[g*128 + t] / cnt;
  pooled[t + 64] = gsum[g*128 + 64 + t] / cnt;
  __syncthreads();
  float a = b1[t];
  for (int k=0; k<128; k++) a = fmaf(pooled[k], W1[k*64 + t], a);
  h1[t] = fmaxf(a, 0.f);
  __syncthreads();
  if (t < 32){
    float o = b2[t];
    for (int k=0; k<64; k++) o = fmaf(h1[k], W2[k*32 + t], o);
    out[g*32 + t] = fmaxf(o, 0.f);
  }
}

extern "C" void kernel_launch(void* const* d_in, const int* in_sizes, int n_in,
                              void* d_out, int out_size, void* d_ws, size_t ws_size,
                              hipStream_t stream){
  const float* emb  = (const float*)d_in[0];
  const float* pose = (const float*)d_in[1];
  const int*   ei   = (const int*)d_in[2];
  const int*   batch= (const int*)d_in[3];
  const float* Wpre = (const float*)d_in[4];
  const float* bpre = (const float*)d_in[5];
  const float* Wg1  = (const float*)d_in[6];
  const float* bg1  = (const float*)d_in[7];
  const float* Wg2  = (const float*)d_in[8];
  const float* bg2  = (const float*)d_in[9];
  const float* Wh1  = (const float*)d_in[10];
  const float* bh1  = (const float*)d_in[11];
  const float* Wh2  = (const float*)d_in[12];
  const float* bh2  = (const float*)d_in[13];
  float* out = (float*)d_out;

  char* ws = (char*)d_ws;
  unsigned short* xb0 = (unsigned short*)(ws + 0);          // 12,800,256 ((N_N+1) rows)
  unsigned short* xb1 = (unsigned short*)(ws + 12800256);   // 12,800,256
  unsigned short* Wt1 = (unsigned short*)(ws + 25600512);   // 32,768
  unsigned short* Wt2 = (unsigned short*)(ws + 25633280);   // 32,768
  int2*  sd   = (int2*) (ws + 25666048);   // 400,000
  float* dinv = (float*)(ws + 26066048);   // 200,000
  int*   ssrc = (int*)  (ws + 26266048);   // NBKT*CAP*4 = 4,804,608
  unsigned int* bins = (unsigned int*)(ws + 31070656);   // 4,804,608
  // contiguous zero region: bcnt | gsum | gcnt
  int*   bcnt = (int*)  (ws + 35875264);   // 3,136
  float* gsum = (float*)(ws + 35878400);   // 65,536
  float* gcnt = (float*)(ws + 35943936);   // 512

  const int ZN = (3136 + 65536 + 512) / 4;   // 17,296 ints
  const int ZB = (ZN + 255)/256;             // 68 blocks

  k_init<<<128 + ZB + 1, 256, 0, stream>>>(Wg1, Wg2, Wt1, Wt2, bcnt, ZN,
                                           (unsigned int*)xb0, (unsigned int*)xb1);

  k_bin<<<BINB, 512, 0, stream>>>(ei, bcnt, bins);
  k_csrpre<<<NBKT, 256, 0, stream>>>(bins, bcnt, sd, dinv, ssrc,
                                     emb, pose, Wpre, bpre, xb0);                 // CSR + x1~ -> xb0

  k_layer<<<N_N/16, 256, 0, stream>>>((const unsigned int*)xb0, sd, ssrc, dinv,
                                      Wt1, bg1, xb1, 1);                          // x2~ -> xb1
  k_layer<<<N_N/16, 256, 0, stream>>>((const unsigned int*)xb1, sd, ssrc, dinv,
                                      Wt2, bg2, xb0, 0);                          // x3 -> xb0

  k_pool<<<(N_N+127)/128, 128, 0, stream>>>(xb0, batch, gsum, gcnt);
  k_head<<<NG, 64, 0, stream>>>(gsum, gcnt, Wh1, bh1, Wh2, bh2, out);
}